// Round 6
// baseline (155.729 us; speedup 1.0000x reference)
//
#include <hip/hip_runtime.h>
#include <stdint.h>

typedef unsigned int u32;
typedef unsigned long long u64;

#define TOPK 100
#define CAP 4096
#define NB 512
#define BINBASE 32000u     // (0x3E800000 >> 15): bin 0 == 0.25f
#define KA_BLOCKS 788      // kA: task = (2px, anchor); L0 153600, L1 38400, L2 9600
#define KBT_BLOCKS 198     // kBT: 1024-thread blocks; L0 150, L1 38, L2 10
#define FIN_BASE (KBT_BLOCKS - 5)   // done-counter value of the first "finisher"

__device__ const float ANC[3][3][2] = {
  {{12.f,16.f},{19.f,36.f},{40.f,28.f}},
  {{36.f,75.f},{76.f,55.f},{72.f,146.f}},
  {{142.f,110.f},{192.f,243.f},{459.f,401.f}}
};

__device__ __forceinline__ float sigmoidf_(float x) {
  if (x >= 0.f) return 1.f / (1.f + expf(-x));
  float e = expf(x);
  return e / (1.f + e);
}

__device__ __forceinline__ float fcomp2(const float2& v, int q) {
  return q ? v.y : v.x;
}

// ---------------- kA: scan -> amax per (anchor,2px) + per-level histogram of anchor maxima ----------------
__global__ __launch_bounds__(256) void kA_scan(
    const float* __restrict__ obj0, const float* __restrict__ cls0,
    const float* __restrict__ obj1, const float* __restrict__ cls1,
    const float* __restrict__ obj2, const float* __restrict__ cls2,
    u32* __restrict__ hist, float* __restrict__ amax)
{
  __shared__ u32 h[NB];
  int tid = threadIdx.x;
  h[tid] = 0; h[tid + 256] = 0;
  __syncthreads();

  int b = blockIdx.x;
  const float *obj, *cls; int P, L, abase; u32 task;
  if (b < 600)      { L=0; obj=obj0; cls=cls0; P=102400; abase=0;      task=(u32)(b*256+tid); }
  else if (b < 750) { L=1; obj=obj1; cls=cls1; P=25600;  abase=307200; task=(u32)((b-600)*256+tid); }
  else              { L=2; obj=obj2; cls=cls2; P=6400;   abase=384000; task=(u32)((b-750)*256+tid); }
  int tpa = P >> 1;
  bool valid = task < (u32)(3*tpa);

  if (valid) {
    int a = (int)(task / (u32)tpa), rem = (int)(task % (u32)tpa);
    int p0 = rem * 2;
    float2 o2 = *(const float2*)(obj + a*P + p0);
    const float* cp = cls + (size_t)(a*20)*P + p0;
    float2 cv[20];
    #pragma unroll
    for (int k = 0; k < 20; ++k) cv[k] = *(const float2*)(cp + (size_t)k*P);
    float2 cm = cv[0];
    #pragma unroll
    for (int k = 1; k < 20; ++k) {
      cm.x = fmaxf(cm.x, cv[k].x); cm.y = fmaxf(cm.y, cv[k].y);
    }
    // sigmoid monotone: max_k sig(o)*sig(c_k) == sig(o)*sig(max_k c_k)
    float2 am2;
    am2.x = sigmoidf_(o2.x) * sigmoidf_(cm.x);
    am2.y = sigmoidf_(o2.y) * sigmoidf_(cm.y);
    *(float2*)(amax + abase + a*P + p0) = am2;
    #pragma unroll
    for (int q = 0; q < 2; ++q) {
      u32 bt = __float_as_uint(fcomp2(am2, q));
      if (bt >= (BINBASE << 15)) {
        u32 bin = (bt >> 15) - BINBASE;
        if (bin < NB) atomicAdd(&h[bin], 1u);
      }
    }
  }
  __syncthreads();
  if (h[tid])       atomicAdd(&hist[L*NB + tid],       h[tid]);
  if (h[tid + 256]) atomicAdd(&hist[L*NB + tid + 256], h[tid + 256]);
}

// ---------------- kBT: threshold + collect + (last 5 blocks) select/decode/merge/NMS/output ----------------
// done counter: every block release-increments after its cand stores. Blocks with
// old in [193,197] are "finishers": they spin for done==198 (acquire -> all cand
// visible), run the redundant select, and split the suppression matrix 5 ways
// (roles 0-3 publish chunks via matg+bar; role 4 gathers + greedy + output).
// No circular waits: increments are unconditional and precede all spins.
__global__ __launch_bounds__(1024) void kBT_collect_nms(
    const float* __restrict__ obj0, const float* __restrict__ cls0,
    const float* __restrict__ obj1, const float* __restrict__ cls1,
    const float* __restrict__ obj2, const float* __restrict__ cls2,
    const float* __restrict__ reg0, const float* __restrict__ reg1, const float* __restrict__ reg2,
    const float* __restrict__ amax, const u32* __restrict__ hist,
    u32* __restrict__ cnt, u64* __restrict__ cand,
    u32* __restrict__ done, u32* __restrict__ bar, u64* __restrict__ matg,
    float* __restrict__ out)
{
  extern __shared__ uint8_t smem[];
  u32*    s     = (u32*)(smem);             // [512] threshold scan (aliases mat; sequential use)
  u64*    mat   = (u64*)(smem);             // [1500] tail: Phase A key cache, then matrix rows
  float4* ibox4 = (float4*)(smem + 12000);  // [300] sorted boxes -> 16800
  float2* iml2  = (float2*)(smem + 16800);  // [300] (area, label) -> 19200
  float*  x1s   = (float*)(smem + 19200);
  float*  y1s   = (float*)(smem + 20400);
  float*  x2s   = (float*)(smem + 21600);
  float*  y2s   = (float*)(smem + 22800);
  float*  sc2   = (float*)(smem + 24000);
  int*    lb2   = (int*)(smem + 25200);
  int*    vd2   = (int*)(smem + 26400);
  u64*    rowAny= (u64*)(smem + 27600);     // [5]
  u64*    km    = (u64*)(smem + 27648);     // [5]
  float*  ars   = (float*)(smem + 27696);   // [300] -> 28896
  u64*    sel   = (u64*)(smem + 32800);     // [300] -> 35200
  float*  bxs   = (float*)(smem + 35200);   // [1200] -> 40000
  float*  scs   = (float*)(smem + 40000);   // -> 41200
  int*    lbs   = (int*)(smem + 41200);     // -> 42400
  int*    vds   = (int*)(smem + 42400);     // -> 43600
  __shared__ u32 sThr;
  __shared__ u32 sOld;

  int tid = threadIdx.x;
  int b = blockIdx.x;

  const float *obj, *cls; int P, L, abase; u32 task;
  if (b < 150)      { L=0; obj=obj0; cls=cls0; P=102400; abase=0;      task=(u32)(b*1024+tid); }
  else if (b < 188) { L=1; obj=obj1; cls=cls1; P=25600;  abase=307200; task=(u32)((b-150)*1024+tid); }
  else              { L=2; obj=obj2; cls=cls2; P=6400;   abase=384000; task=(u32)((b-188)*1024+tid); }
  int tpa = P >> 1;
  bool valid = task < (u32)(3*tpa);

  // ---- threshold via suffix scan over this level's histogram ----
  if (tid < NB) s[tid] = hist[L*NB + tid];
  __syncthreads();
  for (int off = 1; off < NB; off <<= 1) {
    u32 v = 0;
    if (tid < NB) v = s[tid] + ((tid + off < NB) ? s[tid + off] : 0u);
    __syncthreads();
    if (tid < NB) s[tid] = v;
    __syncthreads();
  }
  if (tid == 0 && s[0] < TOPK) sThr = BINBASE << 15;   // fallback
  if (tid < NB) {
    u32 a0 = s[tid], n0 = (tid + 1 < NB) ? s[tid + 1] : 0u;
    if (a0 >= TOPK && n0 < TOPK) sThr = (BINBASE + (u32)tid) << 15;
  }
  __syncthreads();
  u32 thr = sThr;

  // ---- collect: amax-gated; agent stores (read back within this kernel by finishers) ----
  if (valid) {
    int a = (int)(task / (u32)tpa), rem = (int)(task % (u32)tpa);
    int p0 = rem * 2;
    float2 am2 = *(const float2*)(amax + abase + a*P + p0);
    bool any = (__float_as_uint(am2.x) >= thr) | (__float_as_uint(am2.y) >= thr);
    if (any) {
      float2 o2 = *(const float2*)(obj + a*P + p0);
      const float* cp = cls + (size_t)(a*20)*P + p0;
      float2 cv[20];
      #pragma unroll
      for (int k = 0; k < 20; ++k) cv[k] = *(const float2*)(cp + (size_t)k*P);
      #pragma unroll
      for (int q = 0; q < 2; ++q) {
        if (__float_as_uint(fcomp2(am2, q)) >= thr) {
          float so = sigmoidf_(fcomp2(o2, q));
          int p = p0 + q;
          #pragma unroll
          for (int k = 0; k < 20; ++k) {
            float sc = so * sigmoidf_(fcomp2(cv[k], q));
            u32 bits = __float_as_uint(sc);
            if (bits >= thr) {
              u32 pos = atomicAdd(&cnt[L], 1u);
              u32 idx = (u32)(p*60 + a*20 + k);
              if (pos < CAP)
                __hip_atomic_store(&cand[L*CAP + pos],
                                   ((u64)bits << 32) | (u64)(0x00FFFFFFu - idx),
                                   __ATOMIC_RELAXED, __HIP_MEMORY_SCOPE_AGENT);
            }
          }
        }
      }
    }
  }
  __syncthreads();   // drains all waves' stores before the release increment

  if (tid == 0) sOld = __hip_atomic_fetch_add(done, 1u, __ATOMIC_ACQ_REL, __HIP_MEMORY_SCOPE_AGENT);
  __syncthreads();
  u32 old = sOld;
  if (old < FIN_BASE) return;          // not a finisher
  int role = (int)(old - FIN_BASE);    // 0..4; role 4 = truly last

  // finishers wait until ALL blocks have published their candidates
  if (tid == 0) {
    while (__hip_atomic_load(done, __ATOMIC_ACQUIRE, __HIP_MEMORY_SCOPE_AGENT) < (u32)KBT_BLOCKS)
      __builtin_amdgcn_s_sleep(1);
  }
  __syncthreads();

  if (tid < 300) sel[tid] = 0ull;
  __syncthreads();

  // ---- Phase A: per-level exact top-100, 3 levels CONCURRENT in wave-aligned groups ----
  {
    int gL    = (tid >= 768) ? 2 : (tid >= 384) ? 1 : 0;
    int gbase = (gL == 2) ? 768 : (gL == 1) ? 384 : 0;
    int lt    = tid - gbase;
    int gsz   = (gL == 2) ? 256 : 384;

    u32 n = __hip_atomic_load(&cnt[gL], __ATOMIC_RELAXED, __HIP_MEMORY_SCOPE_AGENT);
    if (n > CAP) n = CAP;
    bool useLds = (n <= 496);                  // 3*500 u64 fits in mat[1500]
    u64* kc = mat + gL*500;
    const u64* cb = cand + gL*CAP;
    u32 n4 = (n + 3u) & ~3u;

    if (useLds) {
      for (u32 j = (u32)lt; j < n; j += gsz)
        kc[j] = __hip_atomic_load(&cb[j], __ATOMIC_RELAXED, __HIP_MEMORY_SCOPE_AGENT);
      if (lt < 4 && n + (u32)lt < n4) kc[n + lt] = 0ull;   // pad (n4 <= 500)
    }
    __syncthreads();   // uniform barrier

    if (useLds) {
      for (u32 j = (u32)lt; j < n; j += gsz) {
        u64 kk = kc[j]; int r = 0;
        for (u32 t = 0; t < n4; t += 4) {
          u64 k0 = kc[t], k1 = kc[t+1], k2 = kc[t+2], k3 = kc[t+3];
          r += (k0 > kk) ? 1 : 0; r += (k1 > kk) ? 1 : 0;
          r += (k2 > kk) ? 1 : 0; r += (k3 > kk) ? 1 : 0;
        }
        if (r < TOPK) sel[gL*TOPK + r] = kk;
      }
    } else {
      for (u32 j = (u32)lt; j < n; j += gsz) {
        u64 kk = __hip_atomic_load(&cb[j], __ATOMIC_RELAXED, __HIP_MEMORY_SCOPE_AGENT);
        int r = 0;
        for (u32 t = 0; t < n; ++t)
          r += (__hip_atomic_load(&cb[t], __ATOMIC_RELAXED, __HIP_MEMORY_SCOPE_AGENT) > kk) ? 1 : 0;
        if (r < TOPK) sel[gL*TOPK + r] = kk;
      }
    }
  }
  __syncthreads();

  // ---- Phase B: decode selected boxes (by concat position) ----
  if (tid < 300) {
    int Lq = tid / TOPK;
    const float* reg; int Pq, W, stride;
    if (Lq == 0)      { reg = reg0; Pq = 102400; W = 320; stride = 8; }
    else if (Lq == 1) { reg = reg1; Pq = 25600;  W = 160; stride = 16; }
    else              { reg = reg2; Pq = 6400;   W = 80;  stride = 32; }
    u64 key = sel[tid];
    if (key == 0) {
      scs[tid] = 0.f; lbs[tid] = 0; vds[tid] = 0;
      bxs[tid*4+0] = bxs[tid*4+1] = bxs[tid*4+2] = bxs[tid*4+3] = 0.f;
    } else {
      float score = __uint_as_float((u32)(key >> 32));
      u32 i = 0x00FFFFFFu - (u32)(key & 0xFFFFFFFFull);
      int c = (int)(i % 60u), p = (int)(i / 60u);
      int aa = c / 20, k = c % 20;
      int x = p % W, y = p / W;
      float tx = reg[(aa*4+0)*Pq + p], ty = reg[(aa*4+1)*Pq + p];
      float tw = reg[(aa*4+2)*Pq + p], th = reg[(aa*4+3)*Pq + p];
      float cx = (sigmoidf_(tx)*3.f - 1.5f + (float)x + 0.5f) * (float)stride;
      float cy = (sigmoidf_(ty)*3.f - 1.5f + (float)y + 0.5f) * (float)stride;
      float bw = expf(tw) * ANC[Lq][aa][0];
      float bh = expf(th) * ANC[Lq][aa][1];
      scs[tid] = score; lbs[tid] = k; vds[tid] = (score > 0.01f) ? 1 : 0;
      bxs[tid*4+0] = cx - 0.5f*bw; bxs[tid*4+1] = cy - 0.5f*bh;
      bxs[tid*4+2] = cx + 0.5f*bw; bxs[tid*4+3] = cy + 0.5f*bh;
    }
  }
  __syncthreads();

  // ---- Phase C: 3-way merge of per-level sorted lists (stable == jnp argsort(-scores)) ----
  if (tid < 300) {
    int Lm = tid / TOPK, rr = tid % TOPK;
    u64 kk = sel[tid];
    int rank = rr;
    #pragma unroll
    for (int Lo = 0; Lo < 3; ++Lo) {
      if (Lo == Lm) continue;
      const u64* arr = sel + Lo*TOPK;
      bool ge = (Lo < Lm);     // earlier level wins ties (stable concat order)
      int lo = 0;
      #pragma unroll
      for (int st = 64; st > 0; st >>= 1) {
        int nxt = lo + st;
        if (nxt <= TOPK) {
          u64 v = arr[nxt - 1];
          bool pred = ge ? (v >= kk) : (v > kk);
          if (pred) lo = nxt;
        }
      }
      rank += lo;
    }
    float x1 = bxs[tid*4+0], y1 = bxs[tid*4+1], x2 = bxs[tid*4+2], y2 = bxs[tid*4+3];
    float ar = (x2 - x1) * (y2 - y1);
    ibox4[rank] = make_float4(x1, y1, x2, y2);
    iml2[rank]  = make_float2(ar, (float)lbs[tid]);
    x1s[rank] = x1; y1s[rank] = y1; x2s[rank] = x2; y2s[rank] = y2; ars[rank] = ar;
    sc2[rank] = scs[tid]; lb2[rank] = lbs[tid]; vd2[rank] = vds[tid];
  }
  __syncthreads();

  // ---- Phase D: this finisher's matrix j-chunk, 16 waves striping i ----
  {
    int w = (role == 4) ? 4 : role;
    int wave = tid >> 6, lane = tid & 63;
    int j = w*64 + lane;
    bool jv = j < 300;
    float jx1=0.f, jy1=0.f, jx2=0.f, jy2=0.f, jar=0.f; float jlb=-1.f;
    if (jv) { jx1=x1s[j]; jy1=y1s[j]; jx2=x2s[j]; jy2=y2s[j]; jar=ars[j]; jlb=(float)lb2[j]; }
    int ilim = (w+1)*64; if (ilim > 300) ilim = 300;
    for (int i = wave; i < ilim; i += 16) {
      float4 B = ibox4[i];          // b128 broadcast
      float2 M = iml2[i];           // b64 broadcast (area, label)
      float xx1 = fmaxf(B.x, jx1), yy1 = fmaxf(B.y, jy1);
      float xx2 = fminf(B.z, jx2), yy2 = fminf(B.w, jy2);
      float inter = fmaxf(1e-10f, xx2-xx1) * fmaxf(1e-10f, yy2-yy1);
      float iou = inter / (M.x + jar - inter);
      bool pred = jv && (iou > 0.5f) && (M.y == jlb);
      u64 m = __ballot(pred);
      if (lane == 0) {
        if (role == 4) mat[i*5 + 4] = m;   // chunk 4 stays in LDS
        else __hip_atomic_store(&matg[i*5 + w], m, __ATOMIC_RELAXED, __HIP_MEMORY_SCOPE_AGENT);
      }
    }
  }
  __syncthreads();   // drains stores before publish

  if (role != 4) {
    if (tid == 0)
      __hip_atomic_fetch_add(bar, 1u, __ATOMIC_RELEASE, __HIP_MEMORY_SCOPE_AGENT);
    return;
  }

  // ---- role 4: wait for chunks 0-3, gather to LDS ----
  if (tid == 0) {
    while (__hip_atomic_load(bar, __ATOMIC_ACQUIRE, __HIP_MEMORY_SCOPE_AGENT) < 4u)
      __builtin_amdgcn_s_sleep(1);
  }
  __syncthreads();
  for (int idx = tid; idx < 1200; idx += 1024) {
    int w2 = idx / 300, i = idx % 300;
    if (i < (w2+1)*64)
      mat[i*5 + w2] = __hip_atomic_load(&matg[i*5 + w2], __ATOMIC_RELAXED, __HIP_MEMORY_SCOPE_AGENT);
  }
  __syncthreads();

  // ---- Phase D2: rowAny[c] bit t = row (c*64+t) suppresses anything above it ----
  {
    bool flag = false;
    if (tid < 300) {
      int c = tid >> 6, bq = tid & 63;
      u64 acc = mat[tid*5 + c] & ((bq == 63) ? 0ull : (~0ull << (bq + 1)));
      for (int w = c + 1; w < 5; ++w) acc |= mat[tid*5 + w];
      flag = (acc != 0ull);
    }
    u64 bal = __ballot(flag);
    if ((tid & 63) == 0 && (tid >> 6) < 5) rowAny[tid >> 6] = bal;
  }
  __syncthreads();

  // ---- Phase E: greedy scan; common path register-only ----
  if (tid < 64) {
    int lane = tid;
    u64 vm[5];
    #pragma unroll
    for (int c = 0; c < 5; ++c) {
      int j = c*64 + lane;
      vm[c] = __ballot((j < 300) && (vd2[j] != 0));
    }
    u64 ra[5];
    #pragma unroll
    for (int c = 0; c < 5; ++c) ra[c] = rowAny[c];
    u64 S[5] = {0,0,0,0,0};
    #pragma unroll
    for (int c = 0; c < 5; ++c) {
      u64 kbits = 0;
      int lim = (c == 4) ? 44 : 64;
      for (int t = 0; t < lim; ++t) {
        u64 kept = ((~(S[c] >> t)) & (vm[c] >> t)) & 1ull;
        kbits |= kept << t;
        if (kept & ((ra[c] >> t) & 1ull)) {
          int i = c*64 + t;
          #pragma unroll
          for (int w = 0; w < 5; ++w)
            if (w >= c) S[w] |= mat[i*5 + w];
        }
      }
      if (lane == 0) km[c] = kbits;
    }
  }
  __syncthreads();

  // ---- Phase F: output ----
  if (tid < 300) {
    float kf = (float)((km[tid >> 6] >> (tid & 63)) & 1ull);
    float4 bq = ibox4[tid];
    out[tid*4+0] = bq.x; out[tid*4+1] = bq.y;
    out[tid*4+2] = bq.z; out[tid*4+3] = bq.w;
    out[1200+tid] = sc2[tid] * kf;
    out[1500+tid] = (float)lb2[tid];
    out[1800+tid] = kf;
  }
}

extern "C" void kernel_launch(void* const* d_in, const int* in_sizes, int n_in,
                              void* d_out, int out_size, void* d_ws, size_t ws_size,
                              hipStream_t stream) {
  const float* obj0 = (const float*)d_in[0];
  const float* cls0 = (const float*)d_in[1];
  const float* reg0 = (const float*)d_in[2];
  const float* obj1 = (const float*)d_in[3];
  const float* cls1 = (const float*)d_in[4];
  const float* reg1 = (const float*)d_in[5];
  const float* obj2 = (const float*)d_in[6];
  const float* cls2 = (const float*)d_in[7];
  const float* reg2 = (const float*)d_in[8];
  float* out = (float*)d_out;

  uint8_t* ws = (uint8_t*)d_ws;
  u32*   hist = (u32*)(ws + 0);          // 3*512*4 = 6144
  u32*   cnt  = (u32*)(ws + 6144);       // 12 -> 6156
  u32*   done = (u32*)(ws + 6156);       // 4  -> 6160
  u32*   bar  = (u32*)(ws + 6160);       // 4  -> 6164
  u64*   cand = (u64*)(ws + 8192);       // 3*4096*8 -> 106496
  u64*   matg = (u64*)(ws + 106496);     // 1500*8 = 12000 -> 118496
  float* amax = (float*)(ws + 118496);   // 403200*4 -> 1731296

  (void)hipMemsetAsync(ws, 0, 6164, stream);   // zero hist + cnt + done + bar

  kA_scan<<<dim3(KA_BLOCKS), dim3(256), 0, stream>>>(
      obj0, cls0, obj1, cls1, obj2, cls2, hist, amax);
  kBT_collect_nms<<<dim3(KBT_BLOCKS), dim3(1024), 43600, stream>>>(
      obj0, cls0, obj1, cls1, obj2, cls2, reg0, reg1, reg2,
      amax, hist, cnt, cand, done, bar, matg, out);
}

// Round 7
// 145.221 us; speedup vs baseline: 1.0724x; 1.0724x over previous
//
#include <hip/hip_runtime.h>
#include <stdint.h>

typedef unsigned int u32;
typedef unsigned long long u64;

#define TOPK 100
#define CAP 4096
#define NB 512
#define BINBASE 32000u     // (0x3E800000 >> 15): bin 0 == 0.25f
#define KAB_BLOCKS 788     // task = (2px, anchor); L0 153600, L1 38400, L2 9600

__device__ const float ANC[3][3][2] = {
  {{12.f,16.f},{19.f,36.f},{40.f,28.f}},
  {{36.f,75.f},{76.f,55.f},{72.f,146.f}},
  {{142.f,110.f},{192.f,243.f},{459.f,401.f}}
};

__device__ __forceinline__ float sigmoidf_(float x) {
  if (x >= 0.f) return 1.f / (1.f + expf(-x));
  float e = expf(x);
  return e / (1.f + e);
}

__device__ __forceinline__ float fcomp2(const float2& v, int q) {
  return q ? v.y : v.x;
}

// ---------------- kA: scan -> amax per (anchor,2px) + per-level histogram of anchor maxima ----------------
__global__ __launch_bounds__(256) void kA_scan(
    const float* __restrict__ obj0, const float* __restrict__ cls0,
    const float* __restrict__ obj1, const float* __restrict__ cls1,
    const float* __restrict__ obj2, const float* __restrict__ cls2,
    u32* __restrict__ hist, float* __restrict__ amax)
{
  __shared__ u32 h[NB];
  int tid = threadIdx.x;
  h[tid] = 0; h[tid + 256] = 0;
  __syncthreads();

  int b = blockIdx.x;
  const float *obj, *cls; int P, L, abase; u32 task;
  if (b < 600)      { L=0; obj=obj0; cls=cls0; P=102400; abase=0;      task=(u32)(b*256+tid); }
  else if (b < 750) { L=1; obj=obj1; cls=cls1; P=25600;  abase=307200; task=(u32)((b-600)*256+tid); }
  else              { L=2; obj=obj2; cls=cls2; P=6400;   abase=384000; task=(u32)((b-750)*256+tid); }
  int tpa = P >> 1;
  bool valid = task < (u32)(3*tpa);

  if (valid) {
    int a = (int)(task / (u32)tpa), rem = (int)(task % (u32)tpa);
    int p0 = rem * 2;
    float2 o2 = *(const float2*)(obj + a*P + p0);
    const float* cp = cls + (size_t)(a*20)*P + p0;
    float2 cv[20];
    #pragma unroll
    for (int k = 0; k < 20; ++k) cv[k] = *(const float2*)(cp + (size_t)k*P);
    float2 cm = cv[0];
    #pragma unroll
    for (int k = 1; k < 20; ++k) {
      cm.x = fmaxf(cm.x, cv[k].x); cm.y = fmaxf(cm.y, cv[k].y);
    }
    // sigmoid monotone: max_k sig(o)*sig(c_k) == sig(o)*sig(max_k c_k)
    float2 am2;
    am2.x = sigmoidf_(o2.x) * sigmoidf_(cm.x);
    am2.y = sigmoidf_(o2.y) * sigmoidf_(cm.y);
    *(float2*)(amax + abase + a*P + p0) = am2;
    #pragma unroll
    for (int q = 0; q < 2; ++q) {
      u32 bt = __float_as_uint(fcomp2(am2, q));
      if (bt >= (BINBASE << 15)) {
        u32 bin = (bt >> 15) - BINBASE;
        if (bin < NB) atomicAdd(&h[bin], 1u);
      }
    }
  }
  __syncthreads();
  if (h[tid])       atomicAdd(&hist[L*NB + tid],       h[tid]);
  if (h[tid + 256]) atomicAdd(&hist[L*NB + tid + 256], h[tid + 256]);
}

// ---------------- kB: per-block threshold (suffix scan) + amax-gated collect ----------------
__global__ __launch_bounds__(256) void kB_collect(
    const float* __restrict__ obj0, const float* __restrict__ cls0,
    const float* __restrict__ obj1, const float* __restrict__ cls1,
    const float* __restrict__ obj2, const float* __restrict__ cls2,
    const float* __restrict__ amax, const u32* __restrict__ hist,
    u32* __restrict__ cnt, u64* __restrict__ cand)
{
  __shared__ u32 s[NB];
  __shared__ u32 sThr;
  int tid = threadIdx.x;
  int b = blockIdx.x;
  const float *obj, *cls; int P, L, abase; u32 task;
  if (b < 600)      { L=0; obj=obj0; cls=cls0; P=102400; abase=0;      task=(u32)(b*256+tid); }
  else if (b < 750) { L=1; obj=obj1; cls=cls1; P=25600;  abase=307200; task=(u32)((b-600)*256+tid); }
  else              { L=2; obj=obj2; cls=cls2; P=6400;   abase=384000; task=(u32)((b-750)*256+tid); }
  int tpa = P >> 1;
  bool valid = task < (u32)(3*tpa);

  s[tid] = hist[L*NB + tid]; s[tid + 256] = hist[L*NB + tid + 256];
  __syncthreads();
  for (int off = 1; off < NB; off <<= 1) {
    u32 v0 = s[tid]       + ((tid + off < NB)       ? s[tid + off]       : 0u);
    u32 v1 = s[tid + 256] + ((tid + 256 + off < NB) ? s[tid + 256 + off] : 0u);
    __syncthreads();
    s[tid] = v0; s[tid + 256] = v1;
    __syncthreads();
  }
  if (tid == 0 && s[0] < TOPK) sThr = BINBASE << 15;   // fallback
  {
    int i0 = tid, i1 = tid + 256;
    u32 a0 = s[i0], n0 = (i0 + 1 < NB) ? s[i0 + 1] : 0u;
    if (a0 >= TOPK && n0 < TOPK) sThr = (BINBASE + (u32)i0) << 15;
    u32 a1 = s[i1], n1 = (i1 + 1 < NB) ? s[i1 + 1] : 0u;
    if (a1 >= TOPK && n1 < TOPK) sThr = (BINBASE + (u32)i1) << 15;
  }
  __syncthreads();
  u32 thr = sThr;

  if (valid) {
    int a = (int)(task / (u32)tpa), rem = (int)(task % (u32)tpa);
    int p0 = rem * 2;
    float2 am2 = *(const float2*)(amax + abase + a*P + p0);
    bool any = (__float_as_uint(am2.x) >= thr) | (__float_as_uint(am2.y) >= thr);
    if (any) {
      // rare path (~hundreds of threads grid-wide); cache-hot reloads
      float2 o2 = *(const float2*)(obj + a*P + p0);
      const float* cp = cls + (size_t)(a*20)*P + p0;
      float2 cv[20];
      #pragma unroll
      for (int k = 0; k < 20; ++k) cv[k] = *(const float2*)(cp + (size_t)k*P);
      #pragma unroll
      for (int q = 0; q < 2; ++q) {
        if (__float_as_uint(fcomp2(am2, q)) >= thr) {
          float so = sigmoidf_(fcomp2(o2, q));
          int p = p0 + q;
          #pragma unroll
          for (int k = 0; k < 20; ++k) {
            float sc = so * sigmoidf_(fcomp2(cv[k], q));
            u32 bits = __float_as_uint(sc);
            if (bits >= thr) {
              u32 pos = atomicAdd(&cnt[L], 1u);
              u32 idx = (u32)(p*60 + a*20 + k);
              if (pos < CAP) cand[L*CAP + pos] = ((u64)bits << 32) | (u64)(0x00FFFFFFu - idx);
            }
          }
        }
      }
    }
  }
}

// ---------------- kT: 5-block tail. All blocks: select + fused decode/merge (redundant).
// Block b computes matrix j-chunk ((b==0)?4:b-1); blocks 1-4 publish via agent stores
// + release counter; block 0 (single spinner) gathers + greedy + output. ----------------
__global__ __launch_bounds__(1024) void kT_select_nms(
    const float* __restrict__ reg0, const float* __restrict__ reg1, const float* __restrict__ reg2,
    const u64* __restrict__ cand, const u32* __restrict__ cnt,
    u64* __restrict__ matg, u32* __restrict__ bar,
    float* __restrict__ out)
{
  extern __shared__ uint8_t smem[];
  u64*    mat   = (u64*)(smem);             // [1500] 12000 B — Phase A key cache, then matrix rows
  float4* ibox4 = (float4*)(smem + 12000);  // [300] sorted boxes (packed) -> 16800
  float2* iml2  = (float2*)(smem + 16800);  // [300] (area, label) -> 19200
  float*  x1s   = (float*)(smem + 19200);   // sorted SoA (j-side)
  float*  y1s   = (float*)(smem + 20400);
  float*  x2s   = (float*)(smem + 21600);
  float*  y2s   = (float*)(smem + 22800);
  float*  sc2   = (float*)(smem + 24000);
  int*    lb2   = (int*)(smem + 25200);
  int*    vd2   = (int*)(smem + 26400);
  u64*    rowAny= (u64*)(smem + 27600);     // [5]
  u64*    km    = (u64*)(smem + 27648);     // [5]
  float*  ars   = (float*)(smem + 27696);   // [300] -> 28896
  u64*    sel   = (u64*)(smem + 28896);     // [300] -> 31296

  int tid = threadIdx.x;
  int b = blockIdx.x;
  if (tid < 300) sel[tid] = 0ull;
  __syncthreads();

  // ---- Phase A: per-level exact top-100, 3 levels CONCURRENT in wave-aligned groups ----
  {
    int gL    = (tid >= 768) ? 2 : (tid >= 384) ? 1 : 0;
    int gbase = (gL == 2) ? 768 : (gL == 1) ? 384 : 0;
    int lt    = tid - gbase;
    int gsz   = (gL == 2) ? 256 : 384;

    u32 n = cnt[gL]; if (n > CAP) n = CAP;
    bool useLds = (n <= 496);                  // 3*500 u64 fits in mat[1500]
    u64* kc = mat + gL*500;
    const u64* cb = cand + gL*CAP;
    u32 n4 = (n + 3u) & ~3u;

    if (useLds) {
      for (u32 j = (u32)lt; j < n; j += gsz) kc[j] = cb[j];
      if (lt < 4 && n + (u32)lt < n4) kc[n + lt] = 0ull;   // pad (n4 <= 500)
    }
    __syncthreads();   // uniform barrier

    if (useLds) {
      for (u32 j = (u32)lt; j < n; j += gsz) {
        u64 kk = kc[j]; int r = 0;
        for (u32 t = 0; t < n4; t += 4) {
          u64 k0 = kc[t], k1 = kc[t+1], k2 = kc[t+2], k3 = kc[t+3];
          r += (k0 > kk) ? 1 : 0; r += (k1 > kk) ? 1 : 0;
          r += (k2 > kk) ? 1 : 0; r += (k3 > kk) ? 1 : 0;
        }
        if (r < TOPK) sel[gL*TOPK + r] = kk;
      }
    } else {
      u32 nn = n & ~3u;
      for (u32 j = (u32)lt; j < n; j += gsz) {
        u64 kk = cb[j]; int r = 0;
        for (u32 t = 0; t < nn; t += 4) {
          r += (cb[t]   > kk) ? 1 : 0; r += (cb[t+1] > kk) ? 1 : 0;
          r += (cb[t+2] > kk) ? 1 : 0; r += (cb[t+3] > kk) ? 1 : 0;
        }
        for (u32 t = nn; t < n; ++t) r += (cb[t] > kk) ? 1 : 0;
        if (r < TOPK) sel[gL*TOPK + r] = kk;
      }
    }
  }
  __syncthreads();

  // ---- Phase BC (fused): decode in registers + 3-way merge rank + direct sorted write ----
  if (tid < 300) {
    int Lm = tid / TOPK, rr = tid % TOPK;
    u64 key = sel[tid];

    // decode (registers only)
    const float* reg; int Pq, W, stride;
    if (Lm == 0)      { reg = reg0; Pq = 102400; W = 320; stride = 8; }
    else if (Lm == 1) { reg = reg1; Pq = 25600;  W = 160; stride = 16; }
    else              { reg = reg2; Pq = 6400;   W = 80;  stride = 32; }
    float x1, y1, x2, y2, score; int lab, vld;
    if (key == 0) {
      x1 = y1 = x2 = y2 = 0.f; score = 0.f; lab = 0; vld = 0;
    } else {
      score = __uint_as_float((u32)(key >> 32));
      u32 i = 0x00FFFFFFu - (u32)(key & 0xFFFFFFFFull);
      int c = (int)(i % 60u), p = (int)(i / 60u);
      int aa = c / 20, k = c % 20;
      int x = p % W, y = p / W;
      float tx = reg[(aa*4+0)*Pq + p], ty = reg[(aa*4+1)*Pq + p];
      float tw = reg[(aa*4+2)*Pq + p], th = reg[(aa*4+3)*Pq + p];
      float cx = (sigmoidf_(tx)*3.f - 1.5f + (float)x + 0.5f) * (float)stride;
      float cy = (sigmoidf_(ty)*3.f - 1.5f + (float)y + 0.5f) * (float)stride;
      float bw = expf(tw) * ANC[Lm][aa][0];
      float bh = expf(th) * ANC[Lm][aa][1];
      lab = k; vld = (score > 0.01f) ? 1 : 0;
      x1 = cx - 0.5f*bw; y1 = cy - 0.5f*bh;
      x2 = cx + 0.5f*bw; y2 = cy + 0.5f*bh;
    }

    // merge rank (stable == jnp argsort(-scores) over concat order)
    int rank = rr;
    #pragma unroll
    for (int Lo = 0; Lo < 3; ++Lo) {
      if (Lo == Lm) continue;
      const u64* arr = sel + Lo*TOPK;
      bool ge = (Lo < Lm);     // earlier level wins ties (stable concat order)
      int lo = 0;
      #pragma unroll
      for (int st = 64; st > 0; st >>= 1) {
        int nxt = lo + st;
        if (nxt <= TOPK) {
          u64 v = arr[nxt - 1];
          bool pred = ge ? (v >= key) : (v > key);
          if (pred) lo = nxt;
        }
      }
      rank += lo;
    }

    float ar = (x2 - x1) * (y2 - y1);
    ibox4[rank] = make_float4(x1, y1, x2, y2);
    iml2[rank]  = make_float2(ar, (float)lab);
    x1s[rank] = x1; y1s[rank] = y1; x2s[rank] = x2; y2s[rank] = y2; ars[rank] = ar;
    sc2[rank] = score; lb2[rank] = lab; vd2[rank] = vld;
  }
  __syncthreads();

  // ---- Phase D: this block's matrix j-chunk, 16 waves striping i ----
  {
    int w = (b == 0) ? 4 : (b - 1);
    int wave = tid >> 6, lane = tid & 63;
    int j = w*64 + lane;
    bool jv = j < 300;
    float jx1=0.f, jy1=0.f, jx2=0.f, jy2=0.f, jar=0.f; float jlb=-1.f;
    if (jv) { jx1=x1s[j]; jy1=y1s[j]; jx2=x2s[j]; jy2=y2s[j]; jar=ars[j]; jlb=(float)lb2[j]; }
    int ilim = (w+1)*64; if (ilim > 300) ilim = 300;
    for (int i = wave; i < ilim; i += 16) {
      float4 B = ibox4[i];          // b128 broadcast
      float2 M = iml2[i];           // b64 broadcast (area, label)
      float xx1 = fmaxf(B.x, jx1), yy1 = fmaxf(B.y, jy1);
      float xx2 = fminf(B.z, jx2), yy2 = fminf(B.w, jy2);
      float inter = fmaxf(1e-10f, xx2-xx1) * fmaxf(1e-10f, yy2-yy1);
      float iou = inter / (M.x + jar - inter);
      bool pred = jv && (iou > 0.5f) && (M.y == jlb);
      u64 m = __ballot(pred);
      if (lane == 0) {
        if (b == 0) mat[i*5 + 4] = m;   // chunk 4 stays in LDS
        else __hip_atomic_store(&matg[i*5 + w], m, __ATOMIC_RELAXED, __HIP_MEMORY_SCOPE_AGENT);
      }
    }
  }
  __syncthreads();   // drains all waves' stores before publish

  if (b != 0) {
    if (tid == 0)
      __hip_atomic_fetch_add(bar, 1u, __ATOMIC_RELEASE, __HIP_MEMORY_SCOPE_AGENT);
    return;
  }

  // ---- block 0: wait for chunks 0-3 (single spinner), gather to LDS ----
  if (tid == 0) {
    while (__hip_atomic_load(bar, __ATOMIC_ACQUIRE, __HIP_MEMORY_SCOPE_AGENT) < 4u)
      __builtin_amdgcn_s_sleep(1);
  }
  __syncthreads();
  for (int idx = tid; idx < 1200; idx += 1024) {
    int w2 = idx / 300, i = idx % 300;
    if (i < (w2+1)*64)
      mat[i*5 + w2] = __hip_atomic_load(&matg[i*5 + w2], __ATOMIC_RELAXED, __HIP_MEMORY_SCOPE_AGENT);
  }
  __syncthreads();

  // ---- Phase D2: rowAny[c] bit t = row (c*64+t) suppresses anything above it ----
  {
    bool flag = false;
    if (tid < 300) {
      int c = tid >> 6, bq = tid & 63;
      u64 acc = mat[tid*5 + c] & ((bq == 63) ? 0ull : (~0ull << (bq + 1)));
      for (int w = c + 1; w < 5; ++w) acc |= mat[tid*5 + w];
      flag = (acc != 0ull);
    }
    u64 bal = __ballot(flag);
    if ((tid & 63) == 0 && (tid >> 6) < 5) rowAny[tid >> 6] = bal;
  }
  __syncthreads();

  // ---- Phase E: greedy scan; common path register-only ----
  if (tid < 64) {
    int lane = tid;
    u64 vm[5];
    #pragma unroll
    for (int c = 0; c < 5; ++c) {
      int j = c*64 + lane;
      vm[c] = __ballot((j < 300) && (vd2[j] != 0));
    }
    u64 ra[5];
    #pragma unroll
    for (int c = 0; c < 5; ++c) ra[c] = rowAny[c];
    u64 S[5] = {0,0,0,0,0};
    #pragma unroll
    for (int c = 0; c < 5; ++c) {
      u64 kbits = 0;
      int lim = (c == 4) ? 44 : 64;
      for (int t = 0; t < lim; ++t) {
        u64 kept = ((~(S[c] >> t)) & (vm[c] >> t)) & 1ull;
        kbits |= kept << t;
        if (kept & ((ra[c] >> t) & 1ull)) {
          int i = c*64 + t;
          #pragma unroll
          for (int w = 0; w < 5; ++w)
            if (w >= c) S[w] |= mat[i*5 + w];
        }
      }
      if (lane == 0) km[c] = kbits;
    }
  }
  __syncthreads();

  // ---- Phase F: output ----
  if (tid < 300) {
    float kf = (float)((km[tid >> 6] >> (tid & 63)) & 1ull);
    float4 bq = ibox4[tid];
    out[tid*4+0] = bq.x; out[tid*4+1] = bq.y;
    out[tid*4+2] = bq.z; out[tid*4+3] = bq.w;
    out[1200+tid] = sc2[tid] * kf;
    out[1500+tid] = (float)lb2[tid];
    out[1800+tid] = kf;
  }
}

extern "C" void kernel_launch(void* const* d_in, const int* in_sizes, int n_in,
                              void* d_out, int out_size, void* d_ws, size_t ws_size,
                              hipStream_t stream) {
  const float* obj0 = (const float*)d_in[0];
  const float* cls0 = (const float*)d_in[1];
  const float* reg0 = (const float*)d_in[2];
  const float* obj1 = (const float*)d_in[3];
  const float* cls1 = (const float*)d_in[4];
  const float* reg1 = (const float*)d_in[5];
  const float* obj2 = (const float*)d_in[6];
  const float* cls2 = (const float*)d_in[7];
  const float* reg2 = (const float*)d_in[8];
  float* out = (float*)d_out;

  uint8_t* ws = (uint8_t*)d_ws;
  u32*   hist = (u32*)(ws + 0);          // 3*512*4 = 6144
  u32*   cnt  = (u32*)(ws + 6144);       // 12 -> 6156
  u32*   bar  = (u32*)(ws + 6156);       // 4  -> 6160
  u64*   cand = (u64*)(ws + 8192);       // 3*4096*8 -> 106496
  u64*   matg = (u64*)(ws + 106496);     // 1500*8 = 12000 -> 118496
  float* amax = (float*)(ws + 118496);   // 403200*4 -> 1731296

  (void)hipMemsetAsync(ws, 0, 6160, stream);   // zero hist + cnt + bar

  kA_scan<<<dim3(KAB_BLOCKS), dim3(256), 0, stream>>>(
      obj0, cls0, obj1, cls1, obj2, cls2, hist, amax);
  kB_collect<<<dim3(KAB_BLOCKS), dim3(256), 0, stream>>>(
      obj0, cls0, obj1, cls1, obj2, cls2, amax, hist, cnt, cand);
  kT_select_nms<<<dim3(5), dim3(1024), 31296, stream>>>(
      reg0, reg1, reg2, cand, cnt, matg, bar, out);
}